// Round 4
// baseline (195.192 us; speedup 1.0000x reference)
//
#include <hip/hip_runtime.h>
#include <hip/hip_bf16.h>

// B=16384, D=512, F=28, GIN=1053 (padded 1088 = 17*64)
// out[0 .. B*512)      = updated (LayerNorm result), fp32
// out[B*512 .. 2*B*512)= game_context = relu(x@Wproj^T+b), fp32

#define NB 16384
#define GINP 1088

typedef __bf16 bf16x8 __attribute__((ext_vector_type(8)));
typedef float f32x4 __attribute__((ext_vector_type(4)));
typedef unsigned short ushort8 __attribute__((ext_vector_type(8)));

__device__ __forceinline__ void gload_lds16(const void* g, void* l) {
  __builtin_amdgcn_global_load_lds(
      (const __attribute__((address_space(1))) void*)g,
      (__attribute__((address_space(3))) void*)l, 16, 0, 0);
}
__device__ __forceinline__ float sigmoidf_(float x) { return 1.0f / (1.0f + expf(-x)); }
__device__ __forceinline__ float bf2f(unsigned short u) {
  unsigned int x = ((unsigned int)u) << 16;
  float f; __builtin_memcpy(&f, &x, 4); return f;
}

// ---------------- prep: X bf16 [NB][1088], vectorized ----------------
__global__ __launch_bounds__(256) void prep_x2(
    const float* __restrict__ team, const float* __restrict__ opp,
    const float* __restrict__ gf, const float* __restrict__ won,
    __hip_bfloat16* __restrict__ X) {
  long idx = (long)blockIdx.x * 256 + threadIdx.x;  // NB*136 slots of 8 cols
  if (idx >= (long)NB * 136) return;
  const int r = (int)(idx / 136);
  const int c8 = (int)(idx % 136) * 8;
  float v[8];
  if (c8 < 512) {
    float4 a = *(const float4*)&team[(size_t)r * 512 + c8];
    float4 b = *(const float4*)&team[(size_t)r * 512 + c8 + 4];
    v[0]=a.x; v[1]=a.y; v[2]=a.z; v[3]=a.w; v[4]=b.x; v[5]=b.y; v[6]=b.z; v[7]=b.w;
  } else if (c8 < 1024) {
    float4 a = *(const float4*)&opp[(size_t)r * 512 + (c8 - 512)];
    float4 b = *(const float4*)&opp[(size_t)r * 512 + (c8 - 512) + 4];
    v[0]=a.x; v[1]=a.y; v[2]=a.z; v[3]=a.w; v[4]=b.x; v[5]=b.y; v[6]=b.z; v[7]=b.w;
  } else if (c8 < 1048) {
    const int g0 = c8 - 1024;
#pragma unroll
    for (int e = 0; e < 8; ++e) v[e] = gf[(size_t)r * 28 + g0 + e];
  } else if (c8 == 1048) {
    v[0] = gf[(size_t)r * 28 + 24]; v[1] = gf[(size_t)r * 28 + 25];
    v[2] = gf[(size_t)r * 28 + 26]; v[3] = gf[(size_t)r * 28 + 27];
    v[4] = won[r]; v[5] = 0.f; v[6] = 0.f; v[7] = 0.f;
  } else {
#pragma unroll
    for (int e = 0; e < 8; ++e) v[e] = 0.f;
  }
  __hip_bfloat16 h[8];
#pragma unroll
  for (int e = 0; e < 8; ++e) h[e] = __float2bfloat16(v[e]);
  *(uint4*)&X[(size_t)r * GINP + c8] = *(const uint4*)h;
}

// ---------------- prep: weights ----------------
// Wpb [512][1088], Wrz [1024][1024] (row q = [W_ih[q] | W_hh[q]], r|z blocks),
// Wn [1024][512] (0-511: W_ih n-block, 512-1023: W_hh n-block),
// Wimp1b [128][512], bcat[2048] = [b_ih+b_hh (r,z) | b_ih_n | b_hh_n]
__global__ __launch_bounds__(256) void prep_w2(
    const float* __restrict__ Wproj, const float* __restrict__ Wih,
    const float* __restrict__ Whh, const float* __restrict__ Wimp1,
    const float* __restrict__ bih, const float* __restrict__ bhh,
    __hip_bfloat16* __restrict__ Wpb, __hip_bfloat16* __restrict__ Wrz,
    __hip_bfloat16* __restrict__ Wn, __hip_bfloat16* __restrict__ Wimp1b,
    float* __restrict__ bcat) {
  long idx = (long)blockIdx.x * 256 + threadIdx.x;
  if (idx < 512L * 1088) {
    int r = (int)(idx / 1088), c = (int)(idx % 1088);
    Wpb[idx] = __float2bfloat16(c < 1053 ? Wproj[(size_t)r * 1053 + c] : 0.f);
    return;
  }
  idx -= 512L * 1088;
  if (idx < 1024L * 1024) {
    int q = (int)(idx >> 10), c = (int)(idx & 1023);
    float v = (c < 512) ? Wih[(size_t)q * 512 + c] : Whh[(size_t)q * 512 + (c - 512)];
    Wrz[idx] = __float2bfloat16(v);
    return;
  }
  idx -= 1024L * 1024;
  if (idx < 1024L * 512) {
    int q = (int)(idx / 512), c = (int)(idx % 512);
    float v = (q < 512) ? Wih[(size_t)(1024 + q) * 512 + c]
                        : Whh[(size_t)(1024 + q - 512) * 512 + c];
    Wn[idx] = __float2bfloat16(v);
    return;
  }
  idx -= 1024L * 512;
  if (idx < 128L * 512) { Wimp1b[idx] = __float2bfloat16(Wimp1[idx]); return; }
  idx -= 128L * 512;
  if (idx < 2048) {
    int j = (int)idx;
    float v;
    if (j < 1024) v = bih[j] + bhh[j];
    else if (j < 1536) v = bih[j];
    else v = bhh[j - 512];
    bcat[j] = v;
  }
}

// ---------------- phase-split GEMM: BM=BN=256, BK=64, 512 thr, 8 waves (2x4) ----------------
// 2-slot LDS dbuf (128 KB). 4 phases/K-tile: P1 quad(m0,n0)+12 ds_reads+stage B(T+1);
// P2 quad(m1,n0)+8 reads; P3 quad(m1,n1)+4 reads+stage A(T+2).h0; P4 quad(m0,n1)+stage A(T+2).h1.
// vmcnt(4) once per K-tile at P4 (A(T+2) stays in flight). Write-safety:
//  - B(T+1)->slot^1 staged at P1: slot^1 B last read at P3 of prev span (barrier-separated).
//  - A(T+2)->slot staged at P3/P4: slot A last read at P2 of this span.
// XOR-swizzle: LDS granule g = G ^ (row&7), pre-swizzled global source, linear LDS dest.
// MODE 0: projection (A=X, W=Wpb, relu, Cf fp32 + Cb bf16, ldc 512, tilesN=2, NT=NTP=17).
// MODE 2: gates (ldc 2048, tilesN=8): tn<4: K=1024 concat-A (s<8:P, s>=8:team), W=Wrz;
//         tn 4,5: A=P,  W=Wn rows 0-511  (NT=8); tn 6,7: A=team, W=Wn rows 512-1023 (NT=8).
template <int MODE>
__global__ __launch_bounds__(512, 1) void gemm_8p(
    const __hip_bfloat16* __restrict__ A0, int lda0,
    const __hip_bfloat16* __restrict__ A1, int lda1,
    const __hip_bfloat16* __restrict__ W0, const __hip_bfloat16* __restrict__ W1,
    const float* __restrict__ bias,
    float* __restrict__ Cf, __hip_bfloat16* __restrict__ Cb,
    int tilesN, int NTP) {
  __shared__ __align__(16) unsigned short ldsA[2 * 256 * 64];
  __shared__ __align__(16) unsigned short ldsB[2 * 256 * 64];

  const int tid = threadIdx.x;
  const int wid = tid >> 6, lane = tid & 63;
  const int wr = wid >> 2, wc = wid & 3;     // 2x4 wave grid; per-wave 128x64
  const int fl = lane & 15, kh = lane >> 4;
  const int gp = lane & 7, rsub = lane >> 3; // staging: granule, row-in-stripe

  int bid = blockIdx.x;
  { const int cpx = gridDim.x >> 3; bid = (bid & 7) * cpx + (bid >> 3); }
  const int tm = bid / tilesN, tn = bid % tilesN;
  const int m0 = tm * 256;

  const __hip_bfloat16* Wp; int ldw, NT;
  if (MODE == 0) { Wp = W0 + (size_t)tn * 256 * GINP; ldw = GINP; NT = NTP; }
  else {
    if (tn < 4)      { Wp = W0 + (size_t)tn * 256 * 1024; ldw = 1024; NT = 16; }
    else if (tn < 6) { Wp = W1 + (size_t)(tn - 4) * 256 * 512; ldw = 512; NT = 8; }
    else             { Wp = W1 + (size_t)(512 + (tn - 6) * 256) * 512; ldw = 512; NT = 8; }
  }
  const float* bp = bias + tn * 256;

  auto stageA = [&](int s, int half) {
    const __hip_bfloat16* Ap; int lda; int k0;
    if (MODE == 0) { Ap = A0; lda = lda0; k0 = s * 64; }
    else if (tn < 4) {
      if (s < 8) { Ap = A0; lda = lda0; k0 = s * 64; }
      else       { Ap = A1; lda = lda1; k0 = (s - 8) * 64; }
    } else if (tn < 6) { Ap = A0; lda = lda0; k0 = s * 64; }
    else               { Ap = A1; lda = lda1; k0 = s * 64; }
    unsigned short* base = &ldsA[(s & 1) * 16384];
#pragma unroll
    for (int c = 0; c < 2; ++c) {
      const int r0 = half * 128 + c * 64;
      const int row = r0 + wid * 8 + rsub;
      const int gl = gp ^ (row & 7);
      gload_lds16(Ap + (size_t)(m0 + row) * lda + k0 + gl * 8,
                  base + (size_t)(r0 + wid * 8) * 64);   // wave-uniform dest
    }
  };
  auto stageB = [&](int s, int half) {
    const int kW = s * 64;
    unsigned short* base = &ldsB[(s & 1) * 16384];
#pragma unroll
    for (int c = 0; c < 2; ++c) {
      const int r0 = half * 128 + c * 64;
      const int row = r0 + wid * 8 + rsub;
      const int gl = gp ^ (row & 7);
      gload_lds16(Wp + (size_t)row * ldw + kW + gl * 8,
                  base + (size_t)(r0 + wid * 8) * 64);
    }
  };
  auto readA = [&](const unsigned short* At, int m, int kk) -> bf16x8 {
    const int row = wr * 128 + m * 16 + fl;
    const int G = kk * 4 + kh;
    return *(const bf16x8*)&At[row * 64 + ((G ^ (row & 7)) * 8)];
  };
  auto readB = [&](const unsigned short* Bt, int n, int kk) -> bf16x8 {
    const int row = wc * 64 + n * 16 + fl;
    const int G = kk * 4 + kh;
    return *(const bf16x8*)&Bt[row * 64 + ((G ^ (row & 7)) * 8)];
  };

  f32x4 acc[8][4];
#pragma unroll
  for (int m = 0; m < 8; ++m)
#pragma unroll
    for (int n = 0; n < 4; ++n) acc[m][n] = (f32x4){0.f, 0.f, 0.f, 0.f};

  // prologue: K-tile 0 (A,B) + K-tile 1 (A) -> vmcnt(4) leaves A(1) in flight
  stageA(0, 0); stageA(0, 1); stageB(0, 0); stageB(0, 1);
  stageA(1, 0); stageA(1, 1);
  asm volatile("s_waitcnt vmcnt(4)" ::: "memory");
  __builtin_amdgcn_s_barrier();

  for (int T = 0; T < NT; ++T) {
    const unsigned short* At = &ldsA[(T & 1) * 16384];
    const unsigned short* Bt = &ldsB[(T & 1) * 16384];
    bf16x8 fa0[4][2], fa1[4][2], fb0[2][2], fb1[2][2];

    // ---- P1: quad(m0,n0) ----
#pragma unroll
    for (int m = 0; m < 4; ++m) { fa0[m][0] = readA(At, m, 0); fa0[m][1] = readA(At, m, 1); }
#pragma unroll
    for (int n = 0; n < 2; ++n) { fb0[n][0] = readB(Bt, n, 0); fb0[n][1] = readB(Bt, n, 1); }
    if (T + 1 < NT) { stageB(T + 1, 0); stageB(T + 1, 1); }
    __builtin_amdgcn_s_barrier();
    __builtin_amdgcn_s_setprio(1);
#pragma unroll
    for (int kk = 0; kk < 2; ++kk)
#pragma unroll
      for (int m = 0; m < 4; ++m)
#pragma unroll
        for (int n = 0; n < 2; ++n)
          acc[m][n] = __builtin_amdgcn_mfma_f32_16x16x32_bf16(fa0[m][kk], fb0[n][kk], acc[m][n], 0, 0, 0);
    __builtin_amdgcn_s_setprio(0);
    __builtin_amdgcn_s_barrier();

    // ---- P2: quad(m1,n0) ----
#pragma unroll
    for (int m = 0; m < 4; ++m) { fa1[m][0] = readA(At, m + 4, 0); fa1[m][1] = readA(At, m + 4, 1); }
    __builtin_amdgcn_s_barrier();
    __builtin_amdgcn_s_setprio(1);
#pragma unroll
    for (int kk = 0; kk < 2; ++kk)
#pragma unroll
      for (int m = 0; m < 4; ++m)
#pragma unroll
        for (int n = 0; n < 2; ++n)
          acc[m + 4][n] = __builtin_amdgcn_mfma_f32_16x16x32_bf16(fa1[m][kk], fb0[n][kk], acc[m + 4][n], 0, 0, 0);
    __builtin_amdgcn_s_setprio(0);
    __builtin_amdgcn_s_barrier();

    // ---- P3: quad(m1,n1) ----
#pragma unroll
    for (int n = 0; n < 2; ++n) { fb1[n][0] = readB(Bt, n + 2, 0); fb1[n][1] = readB(Bt, n + 2, 1); }
    if (T + 2 < NT) stageA(T + 2, 0);
    __builtin_amdgcn_s_barrier();
    __builtin_amdgcn_s_setprio(1);
#pragma unroll
    for (int kk = 0; kk < 2; ++kk)
#pragma unroll
      for (int m = 0; m < 4; ++m)
#pragma unroll
        for (int n = 0; n < 2; ++n)
          acc[m + 4][n + 2] = __builtin_amdgcn_mfma_f32_16x16x32_bf16(fa1[m][kk], fb1[n][kk], acc[m + 4][n + 2], 0, 0, 0);
    __builtin_amdgcn_s_setprio(0);
    __builtin_amdgcn_s_barrier();

    // ---- P4: quad(m0,n1) ----
    if (T + 2 < NT) stageA(T + 2, 1);
    __builtin_amdgcn_s_barrier();
    __builtin_amdgcn_s_setprio(1);
#pragma unroll
    for (int kk = 0; kk < 2; ++kk)
#pragma unroll
      for (int m = 0; m < 4; ++m)
#pragma unroll
        for (int n = 0; n < 2; ++n)
          acc[m][n + 2] = __builtin_amdgcn_mfma_f32_16x16x32_bf16(fa0[m][kk], fb1[n][kk], acc[m][n + 2], 0, 0, 0);
    __builtin_amdgcn_s_setprio(0);
    if (T + 2 < NT) { asm volatile("s_waitcnt vmcnt(4)" ::: "memory"); }
    else            { asm volatile("s_waitcnt vmcnt(0)" ::: "memory"); }
    __builtin_amdgcn_s_barrier();
  }

  // Epilogue: C/D map col = lane&15, row = (lane>>4)*4 + j (verified rounds 1-3)
#pragma unroll
  for (int m = 0; m < 8; ++m)
#pragma unroll
    for (int n = 0; n < 4; ++n)
#pragma unroll
      for (int j = 0; j < 4; ++j) {
        const int lrow = wr * 128 + m * 16 + kh * 4 + j;
        const int lcol = wc * 64 + n * 16 + fl;
        const size_t grow = (size_t)(m0 + lrow);
        float v = acc[m][n][j] + bp[lcol];
        if (MODE == 0) {
          v = fmaxf(v, 0.f);
          Cf[grow * 512 + tn * 256 + lcol] = v;
          Cb[grow * 512 + tn * 256 + lcol] = __float2bfloat16(v);
        } else {
          Cb[grow * 2048 + tn * 256 + lcol] = __float2bfloat16(v);
        }
      }
}

// ---------------- h1 GEMM (round-1-verified 128x128 structure, N=128) ----------------
__global__ __launch_bounds__(256, 2) void gemm_imp(
    const __hip_bfloat16* __restrict__ A, const __hip_bfloat16* __restrict__ W,
    const float* __restrict__ bias, float* __restrict__ Cf) {
  __shared__ __align__(16) unsigned short ldsA[128 * 64];
  __shared__ __align__(16) unsigned short ldsB[128 * 64];
  const int tid = threadIdx.x;
  const int w = tid >> 6, lane = tid & 63;
  const int wr = w >> 1, wc = w & 1;
  const int fl = lane & 15, kh = lane >> 4;
  const int srow = lane >> 3, scol = (lane & 7) * 8;
  const int m0 = blockIdx.x * 128;

  f32x4 acc[4][4];
#pragma unroll
  for (int m = 0; m < 4; ++m)
#pragma unroll
    for (int n = 0; n < 4; ++n) acc[m][n] = (f32x4){0.f, 0.f, 0.f, 0.f};

  for (int kt = 0; kt < 8; ++kt) {
    const int k0 = kt * 64;
#pragma unroll
    for (int c = 0; c < 4; ++c) {
      const int rgrp = c * 4 + w;
      const int row = rgrp * 8 + srow;
      gload_lds16(A + (size_t)(m0 + row) * 512 + k0 + scol, (char*)ldsA + rgrp * 1024);
      gload_lds16(W + (size_t)row * 512 + k0 + scol, (char*)ldsB + rgrp * 1024);
    }
    __syncthreads();
#pragma unroll
    for (int kk = 0; kk < 2; ++kk) {
      bf16x8 af[4], bfr[4];
#pragma unroll
      for (int m = 0; m < 4; ++m)
        af[m] = *(const bf16x8*)&ldsA[(wr * 64 + m * 16 + fl) * 64 + kk * 32 + kh * 8];
#pragma unroll
      for (int n = 0; n < 4; ++n)
        bfr[n] = *(const bf16x8*)&ldsB[(wc * 64 + n * 16 + fl) * 64 + kk * 32 + kh * 8];
#pragma unroll
      for (int m = 0; m < 4; ++m)
#pragma unroll
        for (int n = 0; n < 4; ++n)
          acc[m][n] = __builtin_amdgcn_mfma_f32_16x16x32_bf16(af[m], bfr[n], acc[m][n], 0, 0, 0);
    }
    __syncthreads();
  }
#pragma unroll
  for (int m = 0; m < 4; ++m)
#pragma unroll
    for (int n = 0; n < 4; ++n)
#pragma unroll
      for (int j = 0; j < 4; ++j) {
        const int lrow = wr * 64 + m * 16 + kh * 4 + j;
        const int lcol = wc * 64 + n * 16 + fl;
        if (lcol < 128)
          Cf[(size_t)(m0 + lrow) * 128 + lcol] = fmaxf(acc[m][n][j] + bias[lcol], 0.f);
      }
}

// ---------------- importance vector ----------------
__global__ __launch_bounds__(256) void imp_k(const float* __restrict__ h1,
                                             const float* __restrict__ w2,
                                             const float* __restrict__ b2,
                                             float* __restrict__ imp) {
  const int row = blockIdx.x * 4 + (threadIdx.x >> 6);
  const int lane = threadIdx.x & 63;
  float p = h1[(size_t)row * 128 + lane] * w2[lane] +
            h1[(size_t)row * 128 + 64 + lane] * w2[64 + lane];
#pragma unroll
  for (int off = 32; off; off >>= 1) p += __shfl_down(p, off);
  if (lane == 0) imp[row] = sigmoidf_(p + b2[0]);
}

// ---------------- fused GRU + blend + LayerNorm (vectorized, 1 wave/row) ----------------
// gg [NB][2048]: [s_r | s_z | i_n | h_n]
__global__ __launch_bounds__(256) void fuse_final2(
    const float* __restrict__ team, const __hip_bfloat16* __restrict__ gg,
    const float* __restrict__ imp, const float* __restrict__ gamma,
    const float* __restrict__ beta, float* __restrict__ out) {
  const int row = blockIdx.x * 4 + (threadIdx.x >> 6);
  const int lane = threadIdx.x & 63;
  const size_t gb = (size_t)row * 2048 + lane * 8;
  ushort8 sr = *(const ushort8*)&gg[gb];
  ushort8 szv = *(const ushort8*)&gg[gb + 512];
  ushort8 inn = *(const ushort8*)&gg[gb + 1024];
  ushort8 hnn = *(const ushort8*)&gg[gb + 1536];
  float4 t0 = *(const float4*)&team[(size_t)row * 512 + lane * 8];
  float4 t1 = *(const float4*)&team[(size_t)row * 512 + lane * 8 + 4];
  const float im = imp[row];
  float tv[8] = {t0.x, t0.y, t0.z, t0.w, t1.x, t1.y, t1.z, t1.w};
  float u[8];
  float s = 0.f, ss = 0.f;
#pragma unroll
  for (int e = 0; e < 8; ++e) {
    const float rg = sigmoidf_(bf2f(sr[e]));
    const float zg = sigmoidf_(bf2f(szv[e]));
    const float ng = tanhf(bf2f(inn[e]) + rg * bf2f(hnn[e]));
    const float ne = (1.f - zg) * ng + zg * tv[e];
    const float uu = tv[e] + im * (ne - tv[e]);
    u[e] = uu; s += uu; ss += uu * uu;
  }
#pragma unroll
  for (int off = 32; off; off >>= 1) {
    s += __shfl_down(s, off);
    ss += __shfl_down(ss, off);
  }
  s = __shfl(s, 0); ss = __shfl(ss, 0);
  const float mu = s * (1.f / 512.f);
  const float inv = rsqrtf(ss * (1.f / 512.f) - mu * mu + 1e-5f);
  float4 g0 = *(const float4*)&gamma[lane * 8], g1 = *(const float4*)&gamma[lane * 8 + 4];
  float4 b0 = *(const float4*)&beta[lane * 8], b1 = *(const float4*)&beta[lane * 8 + 4];
  float gv[8] = {g0.x, g0.y, g0.z, g0.w, g1.x, g1.y, g1.z, g1.w};
  float bv[8] = {b0.x, b0.y, b0.z, b0.w, b1.x, b1.y, b1.z, b1.w};
  float4 o0, o1;
  o0.x = gv[0] * (u[0] - mu) * inv + bv[0];
  o0.y = gv[1] * (u[1] - mu) * inv + bv[1];
  o0.z = gv[2] * (u[2] - mu) * inv + bv[2];
  o0.w = gv[3] * (u[3] - mu) * inv + bv[3];
  o1.x = gv[4] * (u[4] - mu) * inv + bv[4];
  o1.y = gv[5] * (u[5] - mu) * inv + bv[5];
  o1.z = gv[6] * (u[6] - mu) * inv + bv[6];
  o1.w = gv[7] * (u[7] - mu) * inv + bv[7];
  *(float4*)&out[(size_t)row * 512 + lane * 8] = o0;
  *(float4*)&out[(size_t)row * 512 + lane * 8 + 4] = o1;
}

// ---------------- launch ----------------
extern "C" void kernel_launch(void* const* d_in, const int* in_sizes, int n_in,
                              void* d_out, int out_size, void* d_ws, size_t ws_size,
                              hipStream_t stream) {
  const float* team   = (const float*)d_in[0];
  const float* opp    = (const float*)d_in[1];
  const float* gf     = (const float*)d_in[2];
  const float* won    = (const float*)d_in[3];
  const float* W_proj = (const float*)d_in[4];
  const float* b_proj = (const float*)d_in[5];
  const float* W_ih   = (const float*)d_in[6];
  const float* b_ih   = (const float*)d_in[7];
  const float* W_hh   = (const float*)d_in[8];
  const float* b_hh   = (const float*)d_in[9];
  const float* gamma  = (const float*)d_in[10];
  const float* beta   = (const float*)d_in[11];
  const float* W_imp1 = (const float*)d_in[12];
  const float* b_imp1 = (const float*)d_in[13];
  const float* W_imp2 = (const float*)d_in[14];
  const float* b_imp2 = (const float*)d_in[15];

  char* ws = (char*)d_ws;
  size_t o = 0;
  __hip_bfloat16* Xbf    = (__hip_bfloat16*)(ws + o); o += (size_t)NB * GINP * 2;
  __hip_bfloat16* Wpb    = (__hip_bfloat16*)(ws + o); o += (size_t)512 * GINP * 2;
  __hip_bfloat16* Wrz    = (__hip_bfloat16*)(ws + o); o += (size_t)1024 * 1024 * 2;
  __hip_bfloat16* Wn     = (__hip_bfloat16*)(ws + o); o += (size_t)1024 * 512 * 2;
  __hip_bfloat16* Wimp1b = (__hip_bfloat16*)(ws + o); o += (size_t)128 * 512 * 2;
  float*          bcat   = (float*)(ws + o);          o += (size_t)2048 * 4;
  __hip_bfloat16* Pbf    = (__hip_bfloat16*)(ws + o); o += (size_t)NB * 512 * 2;
  float*          h1     = (float*)(ws + o);          o += (size_t)NB * 128 * 4;
  float*          imp    = (float*)(ws + o);          o += (size_t)NB * 4;
  __hip_bfloat16* gg     = (__hip_bfloat16*)(ws + o); o += (size_t)NB * 2048 * 2;

  float* out_updated = (float*)d_out;
  float* out_ctx     = (float*)d_out + (size_t)NB * 512;

  prep_x2<<<(NB * 136 + 255) / 256, 256, 0, stream>>>(team, opp, gf, won, Xbf);
  {
    const long total = 512L * 1088 + 1024L * 1024 + 1024L * 512 + 128L * 512 + 2048;
    prep_w2<<<(int)((total + 255) / 256), 256, 0, stream>>>(
        W_proj, W_ih, W_hh, W_imp1, b_ih, b_hh, Wpb, Wrz, Wn, Wimp1b, bcat);
  }
  // projected = relu(X @ Wpb^T + b_proj): M=16384, N=512, K=1088 -> 64x2 = 128 blocks
  gemm_8p<0><<<128, 512, 0, stream>>>(Xbf, GINP, nullptr, 0, Wpb, nullptr, b_proj,
                                      out_ctx, Pbf, 2, 17);
  // h1 = relu(P @ Wimp1^T + b_imp1)
  gemm_imp<<<NB / 128, 256, 0, stream>>>(Pbf, Wimp1b, b_imp1, h1);
  imp_k<<<NB / 4, 256, 0, stream>>>(h1, W_imp2, b_imp2, imp);
  // gates: gg = [s_r | s_z | i_n | h_n]: M=16384, N=2048 -> 64x8 = 512 blocks
  gemm_8p<2><<<512, 512, 0, stream>>>(Pbf, 512, Xbf, GINP, Wrz, Wn, bcat,
                                      nullptr, gg, 8, 0);
  fuse_final2<<<NB / 4, 256, 0, stream>>>(team, gg, imp, gamma, beta, out_updated);
}

// Round 5
// 157.519 us; speedup vs baseline: 1.2392x; 1.2392x over previous
//
#include <hip/hip_runtime.h>
#include <hip/hip_bf16.h>

// B=16384, D=512, F=28, GIN=1053 (padded 1088 = 17*64)
// out[0 .. B*512)      = updated (LayerNorm result), fp32
// out[B*512 .. 2*B*512)= game_context = relu(x@Wproj^T+b), fp32

#define NB 16384
#define GINP 1088

typedef __bf16 bf16x8 __attribute__((ext_vector_type(8)));
typedef float f32x4 __attribute__((ext_vector_type(4)));
typedef unsigned short ushort8 __attribute__((ext_vector_type(8)));

__device__ __forceinline__ void gload_lds16(const void* g, void* l) {
  __builtin_amdgcn_global_load_lds(
      (const __attribute__((address_space(1))) void*)g,
      (__attribute__((address_space(3))) void*)l, 16, 0, 0);
}
// Inline-asm LDS read: invisible to the compiler's vmcnt/lgkmcnt dependency
// model (prevents compiler-inserted vmcnt(0) drains tied to global_load_lds
// writes to the same LDS object). Caller must s_waitcnt lgkmcnt(0) +
// sched_barrier(0) before consuming (rule #18).
__device__ __forceinline__ bf16x8 ds_read128(const unsigned short* l) {
  f32x4 r;
  asm volatile("ds_read_b128 %0, %1"
               : "=v"(r)
               : "v"((const __attribute__((address_space(3))) void*)l));
  bf16x8 out;
  __builtin_memcpy(&out, &r, 16);
  return out;
}
__device__ __forceinline__ float sigmoidf_(float x) { return 1.0f / (1.0f + expf(-x)); }
__device__ __forceinline__ float bf2f(unsigned short u) {
  unsigned int x = ((unsigned int)u) << 16;
  float f; __builtin_memcpy(&f, &x, 4); return f;
}

// ---------------- prep: X bf16 [NB][1088], vectorized ----------------
__global__ __launch_bounds__(256) void prep_x2(
    const float* __restrict__ team, const float* __restrict__ opp,
    const float* __restrict__ gf, const float* __restrict__ won,
    __hip_bfloat16* __restrict__ X) {
  long idx = (long)blockIdx.x * 256 + threadIdx.x;  // NB*136 slots of 8 cols
  if (idx >= (long)NB * 136) return;
  const int r = (int)(idx / 136);
  const int c8 = (int)(idx % 136) * 8;
  float v[8];
  if (c8 < 512) {
    float4 a = *(const float4*)&team[(size_t)r * 512 + c8];
    float4 b = *(const float4*)&team[(size_t)r * 512 + c8 + 4];
    v[0]=a.x; v[1]=a.y; v[2]=a.z; v[3]=a.w; v[4]=b.x; v[5]=b.y; v[6]=b.z; v[7]=b.w;
  } else if (c8 < 1024) {
    float4 a = *(const float4*)&opp[(size_t)r * 512 + (c8 - 512)];
    float4 b = *(const float4*)&opp[(size_t)r * 512 + (c8 - 512) + 4];
    v[0]=a.x; v[1]=a.y; v[2]=a.z; v[3]=a.w; v[4]=b.x; v[5]=b.y; v[6]=b.z; v[7]=b.w;
  } else if (c8 < 1048) {
    const int g0 = c8 - 1024;
#pragma unroll
    for (int e = 0; e < 8; ++e) v[e] = gf[(size_t)r * 28 + g0 + e];
  } else if (c8 == 1048) {
    v[0] = gf[(size_t)r * 28 + 24]; v[1] = gf[(size_t)r * 28 + 25];
    v[2] = gf[(size_t)r * 28 + 26]; v[3] = gf[(size_t)r * 28 + 27];
    v[4] = won[r]; v[5] = 0.f; v[6] = 0.f; v[7] = 0.f;
  } else {
#pragma unroll
    for (int e = 0; e < 8; ++e) v[e] = 0.f;
  }
  __hip_bfloat16 h[8];
#pragma unroll
  for (int e = 0; e < 8; ++e) h[e] = __float2bfloat16(v[e]);
  *(uint4*)&X[(size_t)r * GINP + c8] = *(const uint4*)h;
}

// ---------------- prep: weights ----------------
// Wpb [512][1088], Wrz [1024][1024] (row q = [W_ih[q] | W_hh[q]], r|z blocks),
// Wn [1024][512] (0-511: W_ih n-block, 512-1023: W_hh n-block),
// Wimp1b [128][512], bcat[2048] = [b_ih+b_hh (r,z) | b_ih_n | b_hh_n]
__global__ __launch_bounds__(256) void prep_w2(
    const float* __restrict__ Wproj, const float* __restrict__ Wih,
    const float* __restrict__ Whh, const float* __restrict__ Wimp1,
    const float* __restrict__ bih, const float* __restrict__ bhh,
    __hip_bfloat16* __restrict__ Wpb, __hip_bfloat16* __restrict__ Wrz,
    __hip_bfloat16* __restrict__ Wn, __hip_bfloat16* __restrict__ Wimp1b,
    float* __restrict__ bcat) {
  long idx = (long)blockIdx.x * 256 + threadIdx.x;
  if (idx < 512L * 1088) {
    int r = (int)(idx / 1088), c = (int)(idx % 1088);
    Wpb[idx] = __float2bfloat16(c < 1053 ? Wproj[(size_t)r * 1053 + c] : 0.f);
    return;
  }
  idx -= 512L * 1088;
  if (idx < 1024L * 1024) {
    int q = (int)(idx >> 10), c = (int)(idx & 1023);
    float v = (c < 512) ? Wih[(size_t)q * 512 + c] : Whh[(size_t)q * 512 + (c - 512)];
    Wrz[idx] = __float2bfloat16(v);
    return;
  }
  idx -= 1024L * 1024;
  if (idx < 1024L * 512) {
    int q = (int)(idx / 512), c = (int)(idx % 512);
    float v = (q < 512) ? Wih[(size_t)(1024 + q) * 512 + c]
                        : Whh[(size_t)(1024 + q - 512) * 512 + c];
    Wn[idx] = __float2bfloat16(v);
    return;
  }
  idx -= 1024L * 512;
  if (idx < 128L * 512) { Wimp1b[idx] = __float2bfloat16(Wimp1[idx]); return; }
  idx -= 128L * 512;
  if (idx < 2048) {
    int j = (int)idx;
    float v;
    if (j < 1024) v = bih[j] + bhh[j];
    else if (j < 1536) v = bih[j];
    else v = bhh[j - 512];
    bcat[j] = v;
  }
}

// ---------------- deep-pipelined GEMM: BM=256, BN=128, BK=64, 512 thr ----------------
// Round-3 dataflow (3-deep LDS ring, counted vmcnt(6), XOR-swizzle), but frag
// reads are inline-asm ds_read_b128 so hipcc cannot insert vmcnt(0) drains.
// MODE 0: projection (relu, Cf fp32 + Cb bf16, ldc 512).
// MODE 2: gates (ldc 2048): tn<8: K=1024 concat-A (s<8:P, s>=8:team), W=Wrz
//         (W K-offset monotonic); tn 8-11: A=P, W=Wn[ih_n]; tn 12-15: A=team, W=Wn[hh_n].
template <int MODE>
__global__ __launch_bounds__(512, 1) void gemm_dp3(
    const __hip_bfloat16* __restrict__ A0, int lda0,
    const __hip_bfloat16* __restrict__ A1, int lda1,
    const __hip_bfloat16* __restrict__ W0, const __hip_bfloat16* __restrict__ W1,
    const float* __restrict__ bias,
    float* __restrict__ Cf, __hip_bfloat16* __restrict__ Cb,
    int tilesN, int NTP) {
  __shared__ __align__(16) unsigned short ldsA[3 * 256 * 64];
  __shared__ __align__(16) unsigned short ldsB[3 * 128 * 64];

  const int tid = threadIdx.x;
  const int wid = tid >> 6, lane = tid & 63;
  const int wr = wid >> 1, wc = wid & 1;          // 4x2 wave grid, 64x64 per wave
  const int fl = lane & 15, kh = lane >> 4;

  int bid = blockIdx.x;
  { const int cpx = gridDim.x >> 3; bid = (bid & 7) * cpx + (bid >> 3); }
  const int tm = bid / tilesN, tn = bid % tilesN;
  const int m0 = tm * 256;

  const __hip_bfloat16* Wp; int ldw, NT;
  if (MODE == 0) { Wp = W0 + (size_t)tn * 128 * GINP; ldw = GINP; NT = NTP; }
  else {
    if (tn < 8) { Wp = W0 + (size_t)tn * 128 * 1024; ldw = 1024; NT = 16; }
    else        { Wp = W1 + (size_t)(tn - 8) * 128 * 512; ldw = 512; NT = 8; }
  }
  const float* bp = bias + tn * 128;

  const int prow_b = tid >> 3;   // 0..63
  const int gp = tid & 7;

  auto stageAB = [&](int s, int buf) {
    const int kW = s * 64;
    const __hip_bfloat16* Ap; int lda; int kA;
    if (MODE == 0) { Ap = A0; lda = lda0; kA = s * 64; }
    else if (tn < 8) {
      if (s < 8) { Ap = A0; lda = lda0; kA = s * 64; }
      else       { Ap = A1; lda = lda1; kA = (s - 8) * 64; }
    } else if (tn < 12) { Ap = A0; lda = lda0; kA = s * 64; }
    else                { Ap = A1; lda = lda1; kA = s * 64; }
    unsigned short* la = &ldsA[buf * (256 * 64)];
    unsigned short* lb = &ldsB[buf * (128 * 64)];
#pragma unroll
    for (int i = 0; i < 4; ++i) {
      const int prow = i * 64 + prow_b;
      const int gl = gp ^ (prow & 7);
      gload_lds16(Ap + (size_t)(m0 + prow) * lda + kA + gl * 8,
                  la + i * 4096 + wid * 512);
    }
#pragma unroll
    for (int i = 0; i < 2; ++i) {
      const int prow = i * 64 + prow_b;
      const int gl = gp ^ (prow & 7);
      gload_lds16(Wp + (size_t)prow * ldw + kW + gl * 8,
                  lb + i * 4096 + wid * 512);
    }
  };

  f32x4 acc[4][4];
#pragma unroll
  for (int m = 0; m < 4; ++m)
#pragma unroll
    for (int n = 0; n < 4; ++n) acc[m][n] = (f32x4){0.f, 0.f, 0.f, 0.f};

  stageAB(0, 0);
  stageAB(1, 1);

  for (int t = 0; t < NT; ++t) {
    const int cur = t % 3;
    if (t + 1 < NT) {
      asm volatile("s_waitcnt vmcnt(6)" ::: "memory");
    } else {
      asm volatile("s_waitcnt vmcnt(0)" ::: "memory");
    }
    __builtin_amdgcn_s_barrier();
    if (t + 2 < NT) stageAB(t + 2, (t + 2) % 3);

    const unsigned short* At = &ldsA[cur * (256 * 64)];
    const unsigned short* Bt = &ldsB[cur * (128 * 64)];
    bf16x8 af[2][4], bfr[2][4];
#pragma unroll
    for (int kk = 0; kk < 2; ++kk) {
#pragma unroll
      for (int m = 0; m < 4; ++m) {
        const int r = wr * 64 + m * 16 + fl;
        const int g = (kk * 4 + kh) ^ (r & 7);
        af[kk][m] = ds_read128(&At[r * 64 + g * 8]);
      }
#pragma unroll
      for (int n = 0; n < 4; ++n) {
        const int r = wc * 64 + n * 16 + fl;
        const int g = (kk * 4 + kh) ^ (r & 7);
        bfr[kk][n] = ds_read128(&Bt[r * 64 + g * 8]);
      }
    }
    asm volatile("s_waitcnt lgkmcnt(0)" ::: "memory");
    __builtin_amdgcn_sched_barrier(0);
    __builtin_amdgcn_s_setprio(1);
#pragma unroll
    for (int kk = 0; kk < 2; ++kk)
#pragma unroll
      for (int m = 0; m < 4; ++m)
#pragma unroll
        for (int n = 0; n < 4; ++n)
          acc[m][n] = __builtin_amdgcn_mfma_f32_16x16x32_bf16(af[kk][m], bfr[kk][n], acc[m][n], 0, 0, 0);
    __builtin_amdgcn_s_setprio(0);
  }

  // Epilogue: C/D map col = lane&15, row = (lane>>4)*4 + j (verified rounds 1-3)
#pragma unroll
  for (int m = 0; m < 4; ++m)
#pragma unroll
    for (int n = 0; n < 4; ++n)
#pragma unroll
      for (int j = 0; j < 4; ++j) {
        const int lrow = wr * 64 + m * 16 + kh * 4 + j;
        const int lcol = wc * 64 + n * 16 + fl;
        const size_t grow = (size_t)(m0 + lrow);
        float v = acc[m][n][j] + bp[lcol];
        if (MODE == 0) {
          v = fmaxf(v, 0.f);
          Cf[grow * 512 + tn * 128 + lcol] = v;
          Cb[grow * 512 + tn * 128 + lcol] = __float2bfloat16(v);
        } else {
          Cb[grow * 2048 + tn * 128 + lcol] = __float2bfloat16(v);
        }
      }
}

// ---------------- importance GEMM + fused dot: imp = sigmoid(relu(P@W1^T+b1)@w2 + b2) ----
// BM=64, N=128, K=512. 256 thr, 4 waves (2x2), per-wave 32x64. No h1 materialization.
__global__ __launch_bounds__(256, 2) void gemm_imp2(
    const __hip_bfloat16* __restrict__ A, const __hip_bfloat16* __restrict__ W,
    const float* __restrict__ bias, const float* __restrict__ w2,
    const float* __restrict__ b2, float* __restrict__ imp) {
  __shared__ __align__(16) unsigned short ldsA[64 * 64];
  __shared__ __align__(16) unsigned short ldsB[128 * 64];
  __shared__ float sdot[64];
  const int tid = threadIdx.x;
  const int w = tid >> 6, lane = tid & 63;
  const int wr = w >> 1, wc = w & 1;
  const int fl = lane & 15, kh = lane >> 4;
  const int srow = lane >> 3, scol = (lane & 7) * 8;
  const int m0 = blockIdx.x * 64;

  if (tid < 64) sdot[tid] = 0.f;

  f32x4 acc[2][4];
#pragma unroll
  for (int m = 0; m < 2; ++m)
#pragma unroll
    for (int n = 0; n < 4; ++n) acc[m][n] = (f32x4){0.f, 0.f, 0.f, 0.f};

  for (int kt = 0; kt < 8; ++kt) {
    const int k0 = kt * 64;
#pragma unroll
    for (int c = 0; c < 2; ++c) {
      const int rgrp = c * 4 + w;                 // 8 groups of 8 rows (A: 64 rows)
      const int row = rgrp * 8 + srow;
      gload_lds16(A + (size_t)(m0 + row) * 512 + k0 + scol, (char*)ldsA + rgrp * 1024);
    }
#pragma unroll
    for (int c = 0; c < 4; ++c) {
      const int rgrp = c * 4 + w;                 // 16 groups (B: 128 rows)
      const int row = rgrp * 8 + srow;
      gload_lds16(W + (size_t)row * 512 + k0 + scol, (char*)ldsB + rgrp * 1024);
    }
    __syncthreads();
#pragma unroll
    for (int kk = 0; kk < 2; ++kk) {
      bf16x8 af[2], bfr[4];
#pragma unroll
      for (int m = 0; m < 2; ++m)
        af[m] = *(const bf16x8*)&ldsA[(wr * 32 + m * 16 + fl) * 64 + kk * 32 + kh * 8];
#pragma unroll
      for (int n = 0; n < 4; ++n)
        bfr[n] = *(const bf16x8*)&ldsB[(wc * 64 + n * 16 + fl) * 64 + kk * 32 + kh * 8];
#pragma unroll
      for (int m = 0; m < 2; ++m)
#pragma unroll
        for (int n = 0; n < 4; ++n)
          acc[m][n] = __builtin_amdgcn_mfma_f32_16x16x32_bf16(af[m], bfr[n], acc[m][n], 0, 0, 0);
    }
    __syncthreads();
  }
  // Epilogue: h1 = relu(acc + b1); partial dot with w2 per row; LDS-reduce; sigmoid.
#pragma unroll
  for (int m = 0; m < 2; ++m)
#pragma unroll
    for (int j = 0; j < 4; ++j) {
      float p = 0.f;
#pragma unroll
      for (int n = 0; n < 4; ++n) {
        const int lcol = wc * 64 + n * 16 + fl;
        const float v = fmaxf(acc[m][n][j] + bias[lcol], 0.f);
        p += v * w2[lcol];
      }
      atomicAdd(&sdot[wr * 32 + m * 16 + kh * 4 + j], p);
    }
  __syncthreads();
  if (tid < 64) imp[m0 + tid] = sigmoidf_(sdot[tid] + b2[0]);
}

// ---------------- fused GRU + blend + LayerNorm (vectorized, 1 wave/row) ----------------
// gg [NB][2048]: [s_r | s_z | i_n | h_n]
__global__ __launch_bounds__(256) void fuse_final2(
    const float* __restrict__ team, const __hip_bfloat16* __restrict__ gg,
    const float* __restrict__ imp, const float* __restrict__ gamma,
    const float* __restrict__ beta, float* __restrict__ out) {
  const int row = blockIdx.x * 4 + (threadIdx.x >> 6);
  const int lane = threadIdx.x & 63;
  const size_t gb = (size_t)row * 2048 + lane * 8;
  ushort8 sr = *(const ushort8*)&gg[gb];
  ushort8 szv = *(const ushort8*)&gg[gb + 512];
  ushort8 inn = *(const ushort8*)&gg[gb + 1024];
  ushort8 hnn = *(const ushort8*)&gg[gb + 1536];
  float4 t0 = *(const float4*)&team[(size_t)row * 512 + lane * 8];
  float4 t1 = *(const float4*)&team[(size_t)row * 512 + lane * 8 + 4];
  const float im = imp[row];
  float tv[8] = {t0.x, t0.y, t0.z, t0.w, t1.x, t1.y, t1.z, t1.w};
  float u[8];
  float s = 0.f, ss = 0.f;
#pragma unroll
  for (int e = 0; e < 8; ++e) {
    const float rg = sigmoidf_(bf2f(sr[e]));
    const float zg = sigmoidf_(bf2f(szv[e]));
    const float ng = tanhf(bf2f(inn[e]) + rg * bf2f(hnn[e]));
    const float ne = (1.f - zg) * ng + zg * tv[e];
    const float uu = tv[e] + im * (ne - tv[e]);
    u[e] = uu; s += uu; ss += uu * uu;
  }
#pragma unroll
  for (int off = 32; off; off >>= 1) {
    s += __shfl_down(s, off);
    ss += __shfl_down(ss, off);
  }
  s = __shfl(s, 0); ss = __shfl(ss, 0);
  const float mu = s * (1.f / 512.f);
  const float inv = rsqrtf(ss * (1.f / 512.f) - mu * mu + 1e-5f);
  float4 g0 = *(const float4*)&gamma[lane * 8], g1 = *(const float4*)&gamma[lane * 8 + 4];
  float4 b0 = *(const float4*)&beta[lane * 8], b1 = *(const float4*)&beta[lane * 8 + 4];
  float gv[8] = {g0.x, g0.y, g0.z, g0.w, g1.x, g1.y, g1.z, g1.w};
  float bv[8] = {b0.x, b0.y, b0.z, b0.w, b1.x, b1.y, b1.z, b1.w};
  float4 o0, o1;
  o0.x = gv[0] * (u[0] - mu) * inv + bv[0];
  o0.y = gv[1] * (u[1] - mu) * inv + bv[1];
  o0.z = gv[2] * (u[2] - mu) * inv + bv[2];
  o0.w = gv[3] * (u[3] - mu) * inv + bv[3];
  o1.x = gv[4] * (u[4] - mu) * inv + bv[4];
  o1.y = gv[5] * (u[5] - mu) * inv + bv[5];
  o1.z = gv[6] * (u[6] - mu) * inv + bv[6];
  o1.w = gv[7] * (u[7] - mu) * inv + bv[7];
  *(float4*)&out[(size_t)row * 512 + lane * 8] = o0;
  *(float4*)&out[(size_t)row * 512 + lane * 8 + 4] = o1;
}

// ---------------- launch ----------------
extern "C" void kernel_launch(void* const* d_in, const int* in_sizes, int n_in,
                              void* d_out, int out_size, void* d_ws, size_t ws_size,
                              hipStream_t stream) {
  const float* team   = (const float*)d_in[0];
  const float* opp    = (const float*)d_in[1];
  const float* gf     = (const float*)d_in[2];
  const float* won    = (const float*)d_in[3];
  const float* W_proj = (const float*)d_in[4];
  const float* b_proj = (const float*)d_in[5];
  const float* W_ih   = (const float*)d_in[6];
  const float* b_ih   = (const float*)d_in[7];
  const float* W_hh   = (const float*)d_in[8];
  const float* b_hh   = (const float*)d_in[9];
  const float* gamma  = (const float*)d_in[10];
  const float* beta   = (const float*)d_in[11];
  const float* W_imp1 = (const float*)d_in[12];
  const float* b_imp1 = (const float*)d_in[13];
  const float* W_imp2 = (const float*)d_in[14];
  const float* b_imp2 = (const float*)d_in[15];

  char* ws = (char*)d_ws;
  size_t o = 0;
  __hip_bfloat16* Xbf    = (__hip_bfloat16*)(ws + o); o += (size_t)NB * GINP * 2;
  __hip_bfloat16* Wpb    = (__hip_bfloat16*)(ws + o); o += (size_t)512 * GINP * 2;
  __hip_bfloat16* Wrz    = (__hip_bfloat16*)(ws + o); o += (size_t)1024 * 1024 * 2;
  __hip_bfloat16* Wn     = (__hip_bfloat16*)(ws + o); o += (size_t)1024 * 512 * 2;
  __hip_bfloat16* Wimp1b = (__hip_bfloat16*)(ws + o); o += (size_t)128 * 512 * 2;
  float*          bcat   = (float*)(ws + o);          o += (size_t)2048 * 4;
  __hip_bfloat16* Pbf    = (__hip_bfloat16*)(ws + o); o += (size_t)NB * 512 * 2;
  float*          imp    = (float*)(ws + o);          o += (size_t)NB * 4;
  __hip_bfloat16* gg     = (__hip_bfloat16*)(ws + o); o += (size_t)NB * 2048 * 2;

  float* out_updated = (float*)d_out;
  float* out_ctx     = (float*)d_out + (size_t)NB * 512;

  prep_x2<<<(NB * 136 + 255) / 256, 256, 0, stream>>>(team, opp, gf, won, Xbf);
  {
    const long total = 512L * 1088 + 1024L * 1024 + 1024L * 512 + 128L * 512 + 2048;
    prep_w2<<<(int)((total + 255) / 256), 256, 0, stream>>>(
        W_proj, W_ih, W_hh, W_imp1, b_ih, b_hh, Wpb, Wrz, Wn, Wimp1b, bcat);
  }
  // projected = relu(X @ Wpb^T + b_proj): M=16384, N=512, K=1088 -> 64x4 = 256 blocks
  gemm_dp3<0><<<256, 512, 0, stream>>>(Xbf, GINP, nullptr, 0, Wpb, nullptr, b_proj,
                                       out_ctx, Pbf, 4, 17);
  // importance: fused h1-GEMM + dot + sigmoid -> imp[NB]
  gemm_imp2<<<NB / 64, 256, 0, stream>>>(Pbf, Wimp1b, b_imp1, W_imp2, b_imp2, imp);
  // gates: gg = [s_r | s_z | i_n | h_n]: M=16384, N=2048 -> 64x16 = 1024 blocks
  gemm_dp3<2><<<1024, 512, 0, stream>>>(Pbf, 512, Xbf, GINP, Wrz, Wn, bcat,
                                        nullptr, gg, 16, 0);
  fuse_final2<<<NB / 4, 256, 0, stream>>>(team, gg, imp, gamma, beta, out_updated);
}